// Round 5
// baseline (201.931 us; speedup 1.0000x reference)
//
#include <hip/hip_runtime.h>
#include <hip/hip_bf16.h>

#define NGROUPS 8   // L=2 labels * S=4 sessions
#define DIM 128
// per-replica layout (floats): [0,1024) sums[8][128], [1024,2048) wsums[8][128], [2048,2056) counts[8]
#define WS_FLOATS 2056
#define NREP 16     // global atomic replicas to cut same-address chains

typedef float f32x4 __attribute__((ext_vector_type(4)));

// x + dpp(x): one step of a VALU-only wave reduction (no LDS pipe)
template <int CTRL>
__device__ __forceinline__ float dpp_add(float x) {
    int s = __builtin_amdgcn_update_dpp(0, __float_as_int(x), CTRL, 0xF, 0xF, true);
    return x + __int_as_float(s);
}

// per-32-lane-half sums: after shr1/2/4/8 + bcast15, lane31 = sum(lanes 0..31),
// lane63 = sum(lanes 32..63). Returns SGPR {1/max(||lo||,1e-8), 1/max(||hi||,1e-8)}.
__device__ __forceinline__ float2 pair_rnorm(float ss) {
    float r = ss;
    r = dpp_add<0x111>(r);  // row_shr:1
    r = dpp_add<0x112>(r);  // row_shr:2
    r = dpp_add<0x114>(r);  // row_shr:4
    r = dpp_add<0x118>(r);  // row_shr:8
    r = dpp_add<0x142>(r);  // row_bcast:15
    // v_rsq_f32; fmin caps at 1e8 == 1/1e-8 (matches reference eps clamp)
    float inv = fminf(__builtin_amdgcn_rsqf(r), 1e8f);
    float a = __int_as_float(__builtin_amdgcn_readlane(__float_as_int(inv), 31));
    float b = __int_as_float(__builtin_amdgcn_readlane(__float_as_int(inv), 63));
    return make_float2(a, b);
}

// G and RN wave-uniform -> scalar branch chain; only owning group's 8 VALU run.
#define ACCUM_HALF(G, V, RN)                                             \
    {                                                                    \
        _Pragma("unroll")                                                \
        for (int gg = 0; gg < NGROUPS; ++gg) {                           \
            if ((G) == gg) {                                             \
                cnt[gg] += 1;                                            \
                sa[gg][0] += (V).x; sa[gg][1] += (V).y;                  \
                sa[gg][2] += (V).z; sa[gg][3] += (V).w;                  \
                wa[gg][0] = fmaf((RN), (V).x, wa[gg][0]);                \
                wa[gg][1] = fmaf((RN), (V).y, wa[gg][1]);                \
                wa[gg][2] = fmaf((RN), (V).z, wa[gg][2]);                \
                wa[gg][3] = fmaf((RN), (V).w, wa[gg][3]);                \
            }                                                            \
        }                                                                \
    }

// one tile = 4 rows held as two row-pairs (V01 rows 0/1, V23 rows 2/3)
#define COMPUTE_TILE(V01, V23, LB, SE)                                   \
    {                                                                    \
        float ss01 = fmaf((V01).x, (V01).x,                              \
                     fmaf((V01).y, (V01).y,                              \
                     fmaf((V01).z, (V01).z, (V01).w * (V01).w)));        \
        float ss23 = fmaf((V23).x, (V23).x,                              \
                     fmaf((V23).y, (V23).y,                              \
                     fmaf((V23).z, (V23).z, (V23).w * (V23).w)));        \
        float2 rn01 = pair_rnorm(ss01);                                  \
        float2 rn23 = pair_rnorm(ss23);                                  \
        int g0 = (LB).x * 4 + (SE).x;                                    \
        int g1 = (LB).y * 4 + (SE).y;                                    \
        int g2 = (LB).z * 4 + (SE).z;                                    \
        int g3 = (LB).w * 4 + (SE).w;                                    \
        f32x4 ha, hb;                                                    \
        ha = lo ? (V01) : zz; hb = lo ? zz : (V01);                      \
        ACCUM_HALF(g0, ha, rn01.x);                                      \
        ACCUM_HALF(g1, hb, rn01.y);                                      \
        ha = lo ? (V23) : zz; hb = lo ? zz : (V23);                      \
        ACCUM_HALF(g2, ha, rn23.x);                                      \
        ACCUM_HALF(g3, hb, rn23.y);                                      \
    }

#define LOAD_TILE(V01, V23, LB, SE, T)                                   \
    {                                                                    \
        const int rr = ((T) * NW + wid) * 4;                             \
        V01 = feat4[(size_t)rr * 32 + lane];                             \
        V23 = feat4[(size_t)rr * 32 + 64 + lane];                        \
        LB = lab4[rr >> 2];                                              \
        SE = ses4[rr >> 2];                                              \
    }

__global__ __launch_bounds__(256, 4)
void csca_accum_kernel(const f32x4* __restrict__ feat4,
                       const int* __restrict__ labels,
                       const int* __restrict__ sessions,
                       float* __restrict__ gws, int B) {
    __shared__ float s_all[WS_FLOATS];
    for (int i = threadIdx.x; i < WS_FLOATS; i += 256) s_all[i] = 0.0f;
    __syncthreads();

    const int lane = threadIdx.x & 63;
    const int wslot = __builtin_amdgcn_readfirstlane(threadIdx.x >> 6);
    const int wid = blockIdx.x * 4 + wslot;               // wave-uniform (SGPR)
    const int NW = gridDim.x * 4;
    const bool lo = lane < 32;
    const f32x4 zz = {0.0f, 0.0f, 0.0f, 0.0f};

    const int4* lab4 = (const int4*)labels;
    const int4* ses4 = (const int4*)sessions;

    float sa[NGROUPS][4], wa[NGROUPS][4];
    int cnt[NGROUPS];
#pragma unroll
    for (int g = 0; g < NGROUPS; ++g) {
        cnt[g] = 0;
#pragma unroll
        for (int k = 0; k < 4; ++k) { sa[g][k] = 0.0f; wa[g][k] = 0.0f; }
    }

    const int fI = B / (NW * 4);
    // three fixed pipeline stages (no register rotation -> no forced vmcnt(0))
    f32x4 a01 = zz, a23 = zz, b01 = zz, b23 = zz;
    int4 alb = {0,0,0,0}, ase = {0,0,0,0}, blb = {0,0,0,0}, bse = {0,0,0,0};

    if (fI > 0) LOAD_TILE(a01, a23, alb, ase, 0);
    if (fI > 1) LOAD_TILE(b01, b23, blb, bse, 1);

    int it = 0;
    // steady state: unrolled by 3, stages keep fixed roles; each load lands
    // 2 compute-slots before its use.
    for (; it + 5 < fI; it += 3) {
        f32x4 c01, c23; int4 clb, cse;
        LOAD_TILE(c01, c23, clb, cse, it + 2);
        COMPUTE_TILE(a01, a23, alb, ase);
        LOAD_TILE(a01, a23, alb, ase, it + 3);
        COMPUTE_TILE(b01, b23, blb, bse);
        LOAD_TILE(b01, b23, blb, bse, it + 4);
        COMPUTE_TILE(c01, c23, clb, cse);
    }
    // drain: up to 5 tiles left; two guarded super-iterations
#pragma unroll
    for (int e = 0; e < 2; ++e) {
        f32x4 c01 = zz, c23 = zz; int4 clb = {0,0,0,0}, cse = {0,0,0,0};
        if (it + 2 < fI) LOAD_TILE(c01, c23, clb, cse, it + 2);
        if (it < fI)     COMPUTE_TILE(a01, a23, alb, ase);
        if (it + 3 < fI) LOAD_TILE(a01, a23, alb, ase, it + 3);
        if (it + 1 < fI) COMPUTE_TILE(b01, b23, blb, bse);
        if (it + 4 < fI) LOAD_TILE(b01, b23, blb, bse, it + 4);
        if (it + 2 < fI) COMPUTE_TILE(c01, c23, clb, cse);
        it += 3;
    }

    // tail rows (empty when B % (NW*4) == 0; kept for generality)
    for (int row = fI * NW * 4 + wid; row < B; row += NW) {
        f32x4 v = zz;
        if (lo) v = feat4[(size_t)row * 32 + lane];
        int g = __builtin_amdgcn_readfirstlane(labels[row] * 4 + sessions[row]);
        float ss = v.x * v.x + v.y * v.y + v.z * v.z + v.w * v.w;
        float2 rn = pair_rnorm(ss);
        ACCUM_HALF(g, v, rn.x);   // upper lanes hold zeros: harmless
    }

    // fold the two wave halves: lane l (<32) ends with dims [4l,4l+3] totals
#pragma unroll
    for (int gg = 0; gg < NGROUPS; ++gg) {
#pragma unroll
        for (int k = 0; k < 4; ++k) {
            sa[gg][k] += __shfl_xor(sa[gg][k], 32);
            wa[gg][k] += __shfl_xor(wa[gg][k], 32);
        }
    }
    if (lo) {
#pragma unroll
        for (int gg = 0; gg < NGROUPS; ++gg) {
#pragma unroll
            for (int k = 0; k < 4; ++k) {
                atomicAdd(&s_all[gg * DIM + lane * 4 + k], sa[gg][k]);
                atomicAdd(&s_all[1024 + gg * DIM + lane * 4 + k], wa[gg][k]);
            }
        }
    }
    if (lane == 0) {
#pragma unroll
        for (int gg = 0; gg < NGROUPS; ++gg)
            atomicAdd(&s_all[2048 + gg], (float)cnt[gg]);
    }
    __syncthreads();

    float* rep = gws + (size_t)(blockIdx.x & (NREP - 1)) * WS_FLOATS;
    for (int i = threadIdx.x; i < WS_FLOATS; i += 256) atomicAdd(&rep[i], s_all[i]);
}

__global__ __launch_bounds__(256)
void csca_finalize_kernel(const float* __restrict__ gws, float* __restrict__ out, float invB) {
    __shared__ float red[WS_FLOATS];
    for (int i = threadIdx.x; i < WS_FLOATS; i += 256) {
        float s = 0.0f;
#pragma unroll
        for (int r = 0; r < NREP; ++r) s += gws[(size_t)r * WS_FLOATS + i];
        red[i] = s;
    }
    __syncthreads();

    if (threadIdx.x < 64) {
        const int lane = threadIdx.x;
        const float* sums  = red;
        const float* wsums = red + 1024;
        const float* cnts  = red + 2048;
        __shared__ float c_lds[NGROUPS][DIM];
        float cnorm2[NGROUPS];
        float cos_sum = 0.0f;

#pragma unroll
        for (int g = 0; g < NGROUPS; ++g) {
            float invc = 1.0f / cnts[g];
            float c0 = sums[g * DIM + lane] * invc;
            float c1 = sums[g * DIM + 64 + lane] * invc;
            c_lds[g][lane] = c0;
            c_lds[g][64 + lane] = c1;
            float w0 = wsums[g * DIM + lane];
            float w1 = wsums[g * DIM + 64 + lane];
            float pcc = c0 * c0 + c1 * c1;
            float pwc = w0 * c0 + w1 * c1;
#pragma unroll
            for (int m = 1; m < 64; m <<= 1) {
                pcc += __shfl_xor(pcc, m);
                pwc += __shfl_xor(pwc, m);
            }
            cnorm2[g] = pcc;
            cos_sum += pwc / fmaxf(sqrtf(pcc), 1e-8f);
        }
        float center_loss = 1.0f - cos_sum * invB;

        float align = 0.0f;
#pragma unroll
        for (int y = 0; y < 2; ++y) {
            float p0 = 0.0f, p1 = 0.0f;
#pragma unroll
            for (int s = 0; s < 4; ++s) {
                p0 += c_lds[4 * y + s][lane];
                p1 += c_lds[4 * y + s][64 + lane];
            }
            p0 *= 0.25f; p1 *= 0.25f;
            float ppp = p0 * p0 + p1 * p1;
#pragma unroll
            for (int m = 1; m < 64; m <<= 1) ppp += __shfl_xor(ppp, m);
            float pn = fmaxf(sqrtf(ppp), 1e-8f);
            float pc = 0.0f;
#pragma unroll
            for (int s = 0; s < 4; ++s) {
                float d = c_lds[4 * y + s][lane] * p0 + c_lds[4 * y + s][64 + lane] * p1;
#pragma unroll
                for (int m = 1; m < 64; m <<= 1) d += __shfl_xor(d, m);
                float cs = d / (fmaxf(sqrtf(cnorm2[4 * y + s]), 1e-8f) * pn);
                pc += 1.0f - cs;
            }
            align = (align + pc) * 0.25f;  // running /S division, faithful to reference
        }

        if (lane == 0) {
            out[0] = center_loss + align;
            out[1] = center_loss;
            out[2] = align;
        }
    }
}

extern "C" void kernel_launch(void* const* d_in, const int* in_sizes, int n_in,
                              void* d_out, int out_size, void* d_ws, size_t ws_size,
                              hipStream_t stream) {
    const float* feat = (const float*)d_in[0];
    const int* labels = (const int*)d_in[1];
    const int* sessions = (const int*)d_in[2];
    const int B = in_sizes[1];          // 1048576 (features are B x 128)
    float* gws = (float*)d_ws;

    hipMemsetAsync(gws, 0, (size_t)NREP * WS_FLOATS * sizeof(float), stream);

    csca_accum_kernel<<<2048, 256, 0, stream>>>((const f32x4*)feat, labels, sessions, gws, B);
    csca_finalize_kernel<<<1, 256, 0, stream>>>(gws, (float*)d_out, 1.0f / (float)B);
}